// Round 4
// baseline (1378.965 us; speedup 1.0000x reference)
//
#include <hip/hip_runtime.h>
#include <hip/hip_bf16.h>

typedef __hip_bfloat16 bf16;

constexpr int N = 25000;
constexpr int E = 250000;
constexpr size_t NB = (size_t)N * 128;            // 3,200,000

// Workspace layout (float element offsets). Total ~26.2 MB.
constexpr size_t OFF_WE   = 0;                    // W_e  [384x128] f32
constexpr size_t OFF_WM1  = OFF_WE + 49152;       // W_m1 [128x256] f32
constexpr size_t OFF_WM2  = OFF_WM1 + 32768;      // W_m2 [256x128] f32
constexpr size_t OFF_BNS  = OFF_WM2 + 32768;      // 256 f32 BN col sums
constexpr size_t OFF_BNQ  = OFF_BNS + 256;        // 256 f32 BN col sumsq
constexpr size_t OFF_FLAG = OFF_BNQ + 256;        // dtype flag (int in slot 0)
constexpr size_t OFF_XN   = OFF_FLAG + 256;       // N f32 ||x|| per row
constexpr size_t OFF_A    = ((OFF_XN + N + 255) / 256) * 256;
// Region A: 2*NB f32, reused three times:
//   phase 1: XA|XB bf16 (bf16 idx [0,2NB) = f32 slots [0,NB))
//   phase 2: DEN [0,NB) f32 | NUM [NB,2NB) f32   (zeroed by k_zero)
//   phase 3: H1 bf16 (bf16 idx [0,N*256) = f32 slots [0,NB)) overlays DEN
constexpr size_t WS_FLOATS = OFF_A + 2 * NB;      // ~6.55M f32 = 26.2 MB

// ---------------- dtype-agnostic access ----------------

__device__ __forceinline__ float b2f(bf16 v) { return __bfloat162float(v); }

__device__ __forceinline__ float ldf(const void* p, size_t i, int bf) {
    return bf ? b2f(((const bf16*)p)[i]) : ((const float*)p)[i];
}
__device__ __forceinline__ void stf(void* p, size_t i, float v, int bf) {
    if (bf) ((bf16*)p)[i] = __float2bfloat16(v);
    else    ((float*)p)[i] = v;
}
// Scalars (t, scale): under bf16 flag prefer bf16 read but fall back to f32
// if the bf16 interpretation is implausible.
__device__ __forceinline__ float lds_scalar(const void* p, int bf) {
    if (!bf) return *(const float*)p;
    float v = b2f(*(const bf16*)p);
    float a = fabsf(v);
    return (a >= 0.0009765625f && a <= 1024.0f) ? v : *(const float*)p;
}
__device__ __forceinline__ int get_flag(const float* ws) {
    return *(const int*)(ws + OFF_FLAG);
}
// e output base inside d_out: skip the x_out region (NB elements of the
// flag-dependent element size).
__device__ __forceinline__ void* e_base(void* d_out, int bf) {
    return bf ? (void*)((bf16*)d_out + NB) : (void*)((float*)d_out + NB);
}

// Block-wide sum for blockDim.x == 128 (2 waves).
__device__ __forceinline__ float block_sum(float v, float* red) {
    #pragma unroll
    for (int off = 32; off; off >>= 1) v += __shfl_xor(v, off, 64);
    int w = threadIdx.x >> 6;
    if ((threadIdx.x & 63) == 0) red[w] = v;
    __syncthreads();
    float r = red[0] + red[1];
    __syncthreads();
    return r;
}

// ---------------- kernels ----------------

// Detect element dtype of x (N(0,1) data). bf16: ~all uint16s have exponent
// field in [110,135]. f32: only ~55% do (mantissa low-halves are uniform).
__global__ void k_detect(const unsigned short* __restrict__ xu, float* __restrict__ ws) {
    __shared__ int cnt;
    if (threadIdx.x == 0) cnt = 0;
    __syncthreads();
    int c = 0;
    for (int i = threadIdx.x; i < 512; i += 256) {
        unsigned e = (xu[i] >> 7) & 0xFFu;
        if (e >= 110u && e <= 135u) c++;
    }
    atomicAdd(&cnt, c);
    __syncthreads();
    if (threadIdx.x == 0) *(int*)(ws + OFF_FLAG) = (cnt >= 460) ? 1 : 0;
}

// Convert weights to f32 in ws; zero BN accumulators.
__global__ void k_init(float* __restrict__ ws, const void* __restrict__ W_e,
                       const void* __restrict__ W_m1, const void* __restrict__ W_m2) {
    int bf = get_flag(ws);
    size_t gid = (size_t)blockIdx.x * blockDim.x + threadIdx.x;
    size_t stride = (size_t)gridDim.x * blockDim.x;
    for (size_t i = gid; i < 49152; i += stride) ws[OFF_WE + i] = ldf(W_e, i, bf);
    for (size_t i = gid; i < 32768; i += stride) ws[OFF_WM1 + i] = ldf(W_m1, i, bf);
    for (size_t i = gid; i < 32768; i += stride) ws[OFF_WM2 + i] = ldf(W_m2, i, bf);
    for (size_t i = gid; i < 512; i += stride) ws[OFF_BNS + i] = 0.0f;
}

// Per node: xa = x@We[0:128] + b_e, xb = x@We[128:256] (bf16 in region A), ||x||.
__global__ __launch_bounds__(128) void k_node_pre(const void* __restrict__ x,
                                                  const void* __restrict__ b_e,
                                                  float* __restrict__ ws) {
    int bf = get_flag(ws);
    int n = blockIdx.x, tid = threadIdx.x;
    __shared__ float xs[128];
    __shared__ float red[2];
    float xv = ldf(x, (size_t)n * 128 + tid, bf);
    xs[tid] = xv;
    __syncthreads();
    const float* W1 = ws + OFF_WE + tid;
    const float* W2 = ws + OFF_WE + 16384 + tid;
    float a1 = ldf(b_e, tid, bf), a2 = 0.f;
    #pragma unroll 8
    for (int k = 0; k < 128; ++k) {
        float xk = xs[k];
        a1 = fmaf(xk, W1[k * 128], a1);
        a2 = fmaf(xk, W2[k * 128], a2);
    }
    bf16* XA = (bf16*)(ws + OFF_A);
    XA[(size_t)n * 128 + tid] = __float2bfloat16(a1);
    XA[NB + (size_t)n * 128 + tid] = __float2bfloat16(a2);
    float s = block_sum(xv * xv, red);
    if (tid == 0) ws[OFF_XN + n] = sqrtf(s);
}

// Per edge: Linear(cat) -> ReLU -> LN -> +edge_attr -> e (written past x_out).
__global__ __launch_bounds__(128) void k_edge1(const void* __restrict__ ea,
                                               const int* __restrict__ ei,
                                               const void* __restrict__ g_e,
                                               const void* __restrict__ be_e,
                                               float* __restrict__ ws,
                                               void* __restrict__ d_out) {
    int bf = get_flag(ws);
    void* eo = e_base(d_out, bf);
    int j = blockIdx.x, tid = threadIdx.x;
    int r = ei[j], cd = ei[E + j];
    __shared__ float eas[128];
    __shared__ float red[2];
    float eav = ldf(ea, (size_t)j * 128 + tid, bf);
    eas[tid] = eav;
    __syncthreads();
    const bf16* XA = (const bf16*)(ws + OFF_A);
    float acc = b2f(XA[(size_t)r * 128 + tid]) + b2f(XA[NB + (size_t)cd * 128 + tid]);
    const float* W3 = ws + OFF_WE + 32768 + tid;
    #pragma unroll 8
    for (int k = 0; k < 128; ++k) acc = fmaf(eas[k], W3[k * 128], acc);
    acc = fmaxf(acc, 0.f);
    float mu = block_sum(acc, red) * (1.f / 128.f);
    float dv = acc - mu;
    float var = block_sum(dv * dv, red) * (1.f / 128.f);
    float ev = dv * rsqrtf(var + 1e-5f) * ldf(g_e, tid, bf) + ldf(be_e, tid, bf) + eav;
    stf(eo, (size_t)j * 128 + tid, ev, bf);
}

// Zero region A (becomes DEN | NUM).
__global__ void k_zero(float* __restrict__ ws) {
    size_t gid = (size_t)blockIdx.x * blockDim.x + threadIdx.x;
    size_t stride = (size_t)gridDim.x * blockDim.x;
    for (size_t i = gid; i < 2 * NB; i += stride) ws[OFF_A + i] = 0.0f;
}

// Per edge: msg = relu(x[row]+e)+eps; ex = exp(msg*t - 15); den += ex; num += msg*ex.
// (softmax shift-invariant; 0 <= msg*t <~ 22 so a fixed shift needs no segment max)
__global__ __launch_bounds__(128) void k_edge2(const void* __restrict__ x,
                                               const int* __restrict__ ei,
                                               const void* __restrict__ t_p,
                                               void* __restrict__ d_out,
                                               float* __restrict__ ws) {
    int bf = get_flag(ws);
    const void* e_in = e_base(d_out, bf);
    int j = blockIdx.x, tid = threadIdx.x;
    int r = ei[j], cd = ei[E + j];
    float t = lds_scalar(t_p, bf);
    float ev = ldf(e_in, (size_t)j * 128 + tid, bf);
    float msg = fmaxf(ldf(x, (size_t)r * 128 + tid, bf) + ev, 0.f) + 1e-7f;
    float ex = expf(msg * t - 15.0f);
    size_t idx = (size_t)cd * 128 + tid;
    atomicAdd(&ws[OFF_A + idx], ex);
    atomicAdd(&ws[OFF_A + NB + idx], msg * ex);
}

// Per node: agg = num/den (0 if empty), out = agg + x, h1 = out@W_m1 + b_m1.
// Writes H1 (bf16) over its own DEN slots (reads happen before writes, sync'd).
__global__ __launch_bounds__(256) void k_node_mid(const void* __restrict__ x,
                                                  const void* __restrict__ b_m1,
                                                  float* __restrict__ ws) {
    int bf = get_flag(ws);
    int n = blockIdx.x, tid = threadIdx.x;
    __shared__ float outs[128];
    if (tid < 128) {
        size_t idx = (size_t)n * 128 + tid;
        float dn = ws[OFF_A + idx];
        float ag = dn > 0.f ? ws[OFF_A + NB + idx] / dn : 0.f;
        outs[tid] = ag + ldf(x, idx, bf);
    }
    __syncthreads();
    const float* WM1 = ws + OFF_WM1 + tid;
    float acc = ldf(b_m1, tid, bf);
    #pragma unroll 8
    for (int k = 0; k < 128; ++k) acc = fmaf(outs[k], WM1[k * 256], acc);
    ((bf16*)(ws + OFF_A))[(size_t)n * 256 + tid] = __float2bfloat16(acc);
}

// BatchNorm statistics: column sums / sumsq of h1 over N rows.
__global__ __launch_bounds__(256) void k_bnstats(float* __restrict__ ws) {
    int t = threadIdx.x;
    const bf16* H1 = (const bf16*)(ws + OFF_A);
    float s = 0.f, q = 0.f;
    for (int r = blockIdx.x; r < N; r += gridDim.x) {
        float v = b2f(H1[(size_t)r * 256 + t]);
        s += v;
        q = fmaf(v, v, q);
    }
    atomicAdd(&ws[OFF_BNS + t], s);
    atomicAdd(&ws[OFF_BNQ + t], q);
}

// Per node: BN+ReLU, h = .@W_m2 + b_m2, MessageNorm, residual + LayerNorm.
__global__ __launch_bounds__(128) void k_node_post(const void* __restrict__ x,
                                                   const void* __restrict__ g_bn,
                                                   const void* __restrict__ b_bn,
                                                   const void* __restrict__ b_m2,
                                                   const void* __restrict__ scale_p,
                                                   const void* __restrict__ g_n,
                                                   const void* __restrict__ b_n,
                                                   float* __restrict__ ws,
                                                   void* __restrict__ x_out) {
    int bf = get_flag(ws);
    int n = blockIdx.x, tid = threadIdx.x;
    __shared__ float hbn[256];
    __shared__ float red[2];
    const bf16* H1 = (const bf16*)(ws + OFF_A);
    const float inv_n = 1.f / (float)N;
    for (int k = tid; k < 256; k += 128) {
        float v = b2f(H1[(size_t)n * 256 + k]);
        float mu = ws[OFF_BNS + k] * inv_n;
        float var = ws[OFF_BNQ + k] * inv_n - mu * mu;
        float hb = (v - mu) * rsqrtf(fmaxf(var, 0.f) + 1e-5f) * ldf(g_bn, k, bf) + ldf(b_bn, k, bf);
        hbn[k] = fmaxf(hb, 0.f);
    }
    __syncthreads();
    const float* WM2 = ws + OFF_WM2 + tid;
    float acc = ldf(b_m2, tid, bf);
    #pragma unroll 8
    for (int k = 0; k < 256; ++k) acc = fmaf(hbn[k], WM2[k * 128], acc);
    float hn2 = block_sum(acc * acc, red);
    float h = acc / fmaxf(sqrtf(hn2), 1e-12f) * ws[OFF_XN + n] * lds_scalar(scale_p, bf);
    float y = ldf(x, (size_t)n * 128 + tid, bf) + h;
    float mu = block_sum(y, red) * (1.f / 128.f);
    float dv = y - mu;
    float var = block_sum(dv * dv, red) * (1.f / 128.f);
    float o = dv * rsqrtf(var + 1e-5f) * ldf(g_n, tid, bf) + ldf(b_n, tid, bf);
    stf(x_out, (size_t)n * 128 + tid, o, bf);
}

// ---------------- launcher ----------------

extern "C" void kernel_launch(void* const* d_in, const int* in_sizes, int n_in,
                              void* d_out, int out_size, void* d_ws, size_t ws_size,
                              hipStream_t stream) {
    const void* x    = d_in[0];
    const void* ea   = d_in[1];
    const int*  ei   = (const int*)d_in[2];
    const void* W_e  = d_in[3];
    const void* b_e  = d_in[4];
    const void* g_e  = d_in[5];
    const void* be_e = d_in[6];
    const void* t_p  = d_in[7];
    const void* W_m1 = d_in[8];
    const void* b_m1 = d_in[9];
    const void* g_bn = d_in[10];
    const void* b_bn = d_in[11];
    const void* W_m2 = d_in[12];
    const void* b_m2 = d_in[13];
    const void* scl  = d_in[14];
    const void* g_n  = d_in[15];
    const void* b_n  = d_in[16];

    float* ws = (float*)d_ws;

    k_detect<<<1, 256, 0, stream>>>((const unsigned short*)x, ws);
    k_init<<<512, 256, 0, stream>>>(ws, W_e, W_m1, W_m2);
    k_node_pre<<<N, 128, 0, stream>>>(x, b_e, ws);
    k_edge1<<<E, 128, 0, stream>>>(ea, ei, g_e, be_e, ws, d_out);
    k_zero<<<2048, 256, 0, stream>>>(ws);
    k_edge2<<<E, 128, 0, stream>>>(x, ei, t_p, d_out, ws);
    k_node_mid<<<N, 256, 0, stream>>>(x, b_m1, ws);
    k_bnstats<<<64, 256, 0, stream>>>(ws);
    k_node_post<<<N, 128, 0, stream>>>(x, g_bn, b_bn, b_m2, scl, g_n, b_n, ws, d_out);
}